// Round 7
// baseline (2973.014 us; speedup 1.0000x reference)
//
#include <hip/hip_runtime.h>

// Dims
constexpr int TSTEPS = 512;
constexpr int FDIM   = 128;
constexpr int HDIM   = 256;
constexpr int G4H    = 1024;   // 4*H
constexpr int TC     = 8;      // time-chunk (xz granularity)
constexpr int NCH    = TSTEPS / TC;
constexpr int KREG   = 96;     // k-pairs whose weights live in registers
constexpr int KLDS   = 32;     // k-pairs whose weights live in LDS (128 KB)

typedef float        f32x2 __attribute__((ext_vector_type(2)));
typedef _Float16     h2    __attribute__((ext_vector_type(2)));
typedef unsigned int u32;
typedef u32          u32x4 __attribute__((ext_vector_type(4)));

#if defined(__has_builtin)
#if __has_builtin(__builtin_amdgcn_fdot2)
#define FDOT2(a, b, c) __builtin_amdgcn_fdot2((a), (b), (c), false)
#endif
#endif
#ifndef FDOT2
#define FDOT2(a, b, c) ((c) + (float)(a)[0] * (float)(b)[0] + (float)(a)[1] * (float)(b)[1])
#endif

__device__ __forceinline__ h2 as_h2(u32 v) { union { u32 u; h2 p; } c; c.u = v; return c.p; }
__device__ __forceinline__ u32 pack_h2(float a, float b) {
    union { h2 p; u32 u; } c; c.p = h2{(_Float16)a, (_Float16)b}; return c.u;
}
__device__ __forceinline__ float sigmf(float z) { return 1.f / (1.f + __expf(-z)); }
__device__ __forceinline__ float tanhf_fast(float z) {
    float a = fabsf(z);
    float e = __expf(-2.f * a);
    float r = (1.f - e) / (1.f + e);
    return z < 0.f ? -r : r;
}

// v7: ONE ROW PER BLOCK — zero inter-block communication (r6 post-mortem:
// the MALL export/poll/import RTT + cross-block rendezvous was ~7k of the
// 8.3k cycles/step; compute floor is 1024). The 4-block group existed only
// because 512 KB rker exceeds LDS; it fits LDS+REGISTERS: KLDS=32 k-pairs
// (128 KB LDS, shared) + KREG=96 k-pairs x 2 cols/thread in VGPRs
// (192/thread x 512 thr = 384 KB). Grid = 256 blocks = 256 rows = 256 CUs.
// No HX / tags / polls / startup barriers; hang impossible.
//
// ws layout (u32): [0..131072) wpk[kp(128)][col(1024)] = fp16 pair
// (rker[2kp][c], rker[2kp+1][c]); [131072..196608) kpk[fp(64)][col(1024)]
// = (kern[2fp][c], kern[2fp+1][c]). 768 KB exactly (ws_size >= 768 KB proven).
//
// Thread (u = tid>>1, p = tid&1) owns gate-cols c0 = p*512+u, c1 = c0+256
// (p0: gates i,f of unit u; p1: gates g,o). xz for (c0,c1) is produced AND
// consumed by the same thread -> xz lives in 8 packed regs, no xzp LDS.
// Gate: 2 shfl_xor(1) swap the pair's z-halves; both threads compute the
// (identical) cell update redundantly; h packed to hpk via shfl_xor(2).
// One __syncthreads per step.

extern "C" __global__ void __launch_bounds__(256)
conv_wpk(const float* __restrict__ kern, const float* __restrict__ rker,
         u32* __restrict__ ws)
{
    for (int i = blockIdx.x * 256 + threadIdx.x; i < 196608; i += gridDim.x * 256) {
        if (i < 131072) {
            const int kp = i >> 10, c = i & 1023;
            ws[i] = pack_h2(rker[(size_t)(2 * kp) * G4H + c],
                            rker[(size_t)(2 * kp + 1) * G4H + c]);
        } else {
            const int j = i - 131072, fp = j >> 10, c = j & 1023;
            ws[i] = pack_h2(kern[(size_t)(2 * fp) * G4H + c],
                            kern[(size_t)(2 * fp + 1) * G4H + c]);
        }
    }
}

extern "C" __global__ void __launch_bounds__(512, 2)
lstm_row(const float* __restrict__ x, const u32* __restrict__ ws,
         const float* __restrict__ w1, const float* __restrict__ b1,
         const float* __restrict__ w2, const float* __restrict__ b2,
         float* __restrict__ out)
{
    const int row = blockIdx.x;
    const int tid = threadIdx.x;
    const int u   = tid >> 1;        // unit 0..255
    const int p   = tid & 1;         // gate-half: 0 -> (i,f), 1 -> (g,o)
    const int c0  = p * 512 + u;
    const int c1  = c0 + 256;

    const u32* const wpk = ws;
    const u32* const kpk = ws + 131072;

    // LDS: 131072 + 2048 + 1024 = 134,144 B (>80 KB -> 1 block/CU inherently)
    __shared__ __align__(16) u32 wlds[KLDS * 1024];  // kp 96..127, all cols
    __shared__ __align__(16) u32 xs[512];            // x fp16 pairs [fp(64)][t(8)]
    __shared__ __align__(16) u32 hpk[2 * 128];       // h fp16 pairs, dbuf [kp]

    // ---- One-time: W -> registers (KREG kp x 2 cols) + LDS (KLDS kp)
    u32 Wr0[KREG], Wr1[KREG];
#pragma unroll
    for (int k = 0; k < KREG; ++k) {
        Wr0[k] = wpk[k * 1024 + c0];
        Wr1[k] = wpk[k * 1024 + c1];
    }
    for (int i = 4 * tid; i < KLDS * 1024; i += 4 * 512)
        *reinterpret_cast<u32x4*>(&wlds[i]) =
            *reinterpret_cast<const u32x4*>(&wpk[KREG * 1024 + i]);
    if (tid < 128) hpk[tid] = 0;  // h(0) = 0 in buf 0 (ordered by SA0 below)

    float cst = 0.f;   // cell state for unit u (held redundantly in the pair)

#pragma unroll 1
    for (int ch = 0; ch < NCH; ++ch) {
        __syncthreads();  // SA0: prev chunk done with xs; (ch=0: init done)

        // ---- Stage x chunk: xs[fp*8+t] == xs[tid] (conflict-free write)
        {
            const int fp = tid >> 3, t = tid & 7;
            const f32x2 xv = *reinterpret_cast<const f32x2*>(
                &x[((size_t)row * TSTEPS + ch * TC + t) * FDIM + 2 * fp]);
            xs[tid] = pack_h2(xv[0], xv[1]);
        }
        __syncthreads();  // SA1: xs ready

        // ---- Phase A: xz[t][c0,c1] -> 8 packed regs (thread-private!)
        u32 xzr[TC];
#pragma unroll
        for (int pass = 0; pass < 2; ++pass) {  // 4 t per pass (reg pressure)
            float acc[8];
#pragma unroll
            for (int i = 0; i < 8; ++i) acc[i] = 0.f;
#pragma unroll 4
            for (int fp = 0; fp < 64; ++fp) {
                const u32 k0 = kpk[fp * 1024 + c0];
                const u32 k1 = kpk[fp * 1024 + c1];
                const u32x4 X = *reinterpret_cast<const u32x4*>(&xs[fp * 8 + pass * 4]);
#pragma unroll
                for (int t4 = 0; t4 < 4; ++t4) {
                    acc[2 * t4 + 0] = FDOT2(as_h2(k0), as_h2(X[t4]), acc[2 * t4 + 0]);
                    acc[2 * t4 + 1] = FDOT2(as_h2(k1), as_h2(X[t4]), acc[2 * t4 + 1]);
                }
            }
#pragma unroll
            for (int t4 = 0; t4 < 4; ++t4)
                xzr[pass * 4 + t4] = pack_h2(acc[2 * t4 + 0], acc[2 * t4 + 1]);
        }

        // ---- Phase B: 8 steps, ONE barrier each. tc unrolled (static xzr idx).
#pragma unroll
        for (int tc = 0; tc < TC; ++tc) {
            const int bufC = tc & 1, bufN = bufC ^ 1;  // ch*TC even -> t&1 == tc&1
            __syncthreads();  // B1: hpk[bufC] complete (prev step / init)

            float a0 = 0.f, a1 = 0.f;
#pragma unroll
            for (int i = 0; i < KREG / 4; ++i) {   // kp 0..95 from registers
                const u32x4 H = *reinterpret_cast<const u32x4*>(&hpk[bufC * 128 + 4 * i]);
#pragma unroll
                for (int j = 0; j < 4; ++j) {
                    a0 = FDOT2(as_h2(Wr0[4 * i + j]), as_h2(H[j]), a0);
                    a1 = FDOT2(as_h2(Wr1[4 * i + j]), as_h2(H[j]), a1);
                }
            }
#pragma unroll
            for (int i = 0; i < KLDS / 4; ++i) {   // kp 96..127 from LDS
                const u32x4 H = *reinterpret_cast<const u32x4*>(
                    &hpk[bufC * 128 + KREG + 4 * i]);
#pragma unroll
                for (int j = 0; j < 4; ++j) {
                    const int kk = 4 * i + j;
                    a0 = FDOT2(as_h2(wlds[kk * 1024 + c0]), as_h2(H[j]), a0);
                    a1 = FDOT2(as_h2(wlds[kk * 1024 + c1]), as_h2(H[j]), a1);
                }
            }

            // z for own 2 cols; swap halves within the (p0,p1) pair
            const h2 xp = as_h2(xzr[tc]);
            const float z0 = a0 + (float)xp[0];
            const float z1 = a1 + (float)xp[1];
            const float y0 = __shfl_xor(z0, 1);
            const float y1 = __shfl_xor(z1, 1);
            const float zi = p ? y0 : z0;
            const float zf = p ? y1 : z1;
            const float zg = p ? z0 : y0;
            const float zo = p ? z1 : y1;
            cst = sigmf(zf) * cst + sigmf(zi) * tanhf_fast(zg);
            const float hn = sigmf(zo) * tanhf_fast(cst);
            const float ho = __shfl_xor(hn, 2);  // h of unit u^1 (same p)
            if ((tid & 3) == 0)                  // even u, p=0 packs the pair
                hpk[bufN * 128 + (u >> 1)] = pack_h2(hn, ho);
            // next B1 orders this write vs reads
        }
    }
    __syncthreads();  // h(512) complete in hpk buf 0 (t=511 wrote bufN=0)

    // ---- Fused head: out[row] = relu(h@w1+b1)@w2 + b2
    float* const hid = (float*)xs;
    if (tid < 100) {
        float aa = b1[tid];
        const _Float16* hph = (const _Float16*)hpk;  // hph[k] == h[k] (pair layout)
#pragma unroll 8
        for (int k = 0; k < HDIM; ++k)
            aa += (float)hph[k] * w1[k * 100 + tid];
        hid[tid] = fmaxf(aa, 0.f);
    }
    __syncthreads();
    if (tid == 0) {
        float v = b2[0];
#pragma unroll 4
        for (int j = 0; j < 100; ++j) v += hid[j] * w2[j];
        out[row] = v;
    }
}

extern "C" void kernel_launch(void* const* d_in, const int* in_sizes, int n_in,
                              void* d_out, int out_size, void* d_ws, size_t ws_size,
                              hipStream_t stream)
{
    const float* x    = (const float*)d_in[0];
    const float* kern = (const float*)d_in[1];
    const float* rker = (const float*)d_in[2];
    const float* w1   = (const float*)d_in[3];
    const float* b1   = (const float*)d_in[4];
    const float* w2   = (const float*)d_in[5];
    const float* b2   = (const float*)d_in[6];
    u32* ws = (u32*)d_ws;  // 768 KB exactly (proven available)

    conv_wpk<<<dim3(768), dim3(256), 0, stream>>>(kern, rker, ws);
    lstm_row<<<dim3(256), dim3(512), 0, stream>>>(x, ws, w1, b1, w2, b2, (float*)d_out);
}